// Round 1
// 411.224 us; speedup vs baseline: 1.0321x; 1.0321x over previous
//
#include <hip/hip_runtime.h>

#define NFFT 1024
#define NT   256
// LDS swizzle: pad every 32 floats by 1 to break power-of-2 stride conflicts
__device__ __forceinline__ int swz(int a) { return a + (a >> 5); }

// One radix-4 Stockham stage (inverse sign), middle stages only (LDS->LDS).
// Reads x (swizzled), writes y (swizzled). Stride L*M = 256 -> +264 swizzled.
template<int L, int M>
__device__ __forceinline__ void stage(const float* __restrict__ xr,
                                      const float* __restrict__ xi,
                                      float* __restrict__ yr,
                                      float* __restrict__ yi,
                                      int t) {
    const int k  = t & (M - 1);
    const int j  = t / M;
    const int rb = swz(t);

    float c0r = xr[rb];        float c0i = xi[rb];
    float c1r = xr[rb + 264];  float c1i = xi[rb + 264];
    float c2r = xr[rb + 528];  float c2i = xi[rb + 528];
    float c3r = xr[rb + 792];  float c3i = xi[rb + 792];

    float d0r = c0r + c2r, d0i = c0i + c2i;
    float d1r = c0r - c2r, d1i = c0i - c2i;
    float d2r = c1r + c3r, d2i = c1i + c3i;
    // d3 = +i*(c1 - c3)   (inverse transform)
    float d3r = c3i - c1i, d3i = c1r - c3r;

    float e0r = d0r + d2r, e0i = d0i + d2i;
    float e2r = d0r - d2r, e2i = d0i - d2i;
    float e1r = d1r + d3r, e1i = d1i + d3i;
    float e3r = d1r - d3r, e3i = d1i - d3i;

    const float base_ang = 6.28318530717958647692f / (float)(4 * L);
    float ang = base_ang * (float)j;     // w1 = exp(+i*ang)
    float w1i, w1r;
    __sincosf(ang, &w1i, &w1r);
    float w2r = w1r * w1r - w1i * w1i;
    float w2i = 2.0f * w1r * w1i;
    float w3r = w2r * w1r - w2i * w1i;
    float w3i = w2r * w1i + w2i * w1r;
    float o1r = w1r * e1r - w1i * e1i;  float o1i = w1r * e1i + w1i * e1r;
    float o2r = w2r * e2r - w2i * e2i;  float o2i = w2r * e2i + w2i * e2r;
    float o3r = w3r * e3r - w3i * e3i;  float o3i = w3r * e3i + w3i * e3r;

    const int wb = k + 4 * j * M;
    yr[swz(wb)]         = e0r;  yi[swz(wb)]         = e0i;
    yr[swz(wb + M)]     = o1r;  yi[swz(wb + M)]     = o1i;
    yr[swz(wb + 2 * M)] = o2r;  yi[swz(wb + 2 * M)] = o2i;
    yr[swz(wb + 3 * M)] = o3r;  yi[swz(wb + 3 * M)] = o3i;
}

__global__ __launch_bounds__(NT, 8) void ifft1024_kernel(
        const float* __restrict__ re, const float* __restrict__ im,
        float* __restrict__ out, size_t im_out_off) {
    __shared__ float Ar[1056], Ai[1056], Br[1056], Bi[1056];

    const int t = threadIdx.x;
    const size_t base = (size_t)blockIdx.x * NFFT;

    // ---- fused global load + first stage<L=256,M=1> ----
    // Inputs of butterfly j=t are at t + {0,256,512,768}: coalesced dword loads.
    {
        const float* rp = re + base + t;
        const float* ip = im + base + t;
        float c0r = __builtin_nontemporal_load(rp);
        float c0i = __builtin_nontemporal_load(ip);
        float c1r = __builtin_nontemporal_load(rp + 256);
        float c1i = __builtin_nontemporal_load(ip + 256);
        float c2r = __builtin_nontemporal_load(rp + 512);
        float c2i = __builtin_nontemporal_load(ip + 512);
        float c3r = __builtin_nontemporal_load(rp + 768);
        float c3i = __builtin_nontemporal_load(ip + 768);

        float d0r = c0r + c2r, d0i = c0i + c2i;
        float d1r = c0r - c2r, d1i = c0i - c2i;
        float d2r = c1r + c3r, d2i = c1i + c3i;
        float d3r = c3i - c1i, d3i = c1r - c3r;

        float e0r = d0r + d2r, e0i = d0i + d2i;
        float e2r = d0r - d2r, e2i = d0i - d2i;
        float e1r = d1r + d3r, e1i = d1i + d3i;
        float e3r = d1r - d3r, e3i = d1i - d3i;

        float ang = 6.28318530717958647692f / 1024.0f * (float)t;
        float w1i, w1r;
        __sincosf(ang, &w1i, &w1r);
        float w2r = w1r * w1r - w1i * w1i;
        float w2i = 2.0f * w1r * w1i;
        float w3r = w2r * w1r - w2i * w1i;
        float w3i = w2r * w1i + w2i * w1r;

        // writes wb = 4t + r: contiguous, swz(4t+r) = swz(4t)+r
        const int wb = swz(4 * t);
        Ar[wb]     = e0r;                   Ai[wb]     = e0i;
        Ar[wb + 1] = w1r * e1r - w1i * e1i; Ai[wb + 1] = w1r * e1i + w1i * e1r;
        Ar[wb + 2] = w2r * e2r - w2i * e2i; Ai[wb + 2] = w2r * e2i + w2i * e2r;
        Ar[wb + 3] = w3r * e3r - w3i * e3i; Ai[wb + 3] = w3r * e3i + w3i * e3r;
    }
    __syncthreads();

    stage<64, 4 >(Ar, Ai, Br, Bi, t); __syncthreads();
    stage<16, 16>(Br, Bi, Ar, Ai, t); __syncthreads();
    stage<4,  64>(Ar, Ai, Br, Bi, t); __syncthreads();

    // ---- fused last stage<L=1,M=256> + global store ----
    // Outputs of butterfly k=t go to t + {0,256,512,768}: coalesced dword stores.
    {
        const int rb = swz(t);
        float c0r = Br[rb];        float c0i = Bi[rb];
        float c1r = Br[rb + 264];  float c1i = Bi[rb + 264];
        float c2r = Br[rb + 528];  float c2i = Bi[rb + 528];
        float c3r = Br[rb + 792];  float c3i = Bi[rb + 792];

        float d0r = c0r + c2r, d0i = c0i + c2i;
        float d1r = c0r - c2r, d1i = c0i - c2i;
        float d2r = c1r + c3r, d2i = c1i + c3i;
        float d3r = c3i - c1i, d3i = c1r - c3r;

        const float s = 1.0f / 1024.0f;   // IFFT normalization
        float* orp = out + base + t;
        float* oip = out + im_out_off + base + t;
        __builtin_nontemporal_store((d0r + d2r) * s, orp);        // e0
        __builtin_nontemporal_store((d0i + d2i) * s, oip);
        __builtin_nontemporal_store((d1r + d3r) * s, orp + 256);  // e1
        __builtin_nontemporal_store((d1i + d3i) * s, oip + 256);
        __builtin_nontemporal_store((d0r - d2r) * s, orp + 512);  // e2
        __builtin_nontemporal_store((d0i - d2i) * s, oip + 512);
        __builtin_nontemporal_store((d1r - d3r) * s, orp + 768);  // e3
        __builtin_nontemporal_store((d1i - d3i) * s, oip + 768);
    }
}

extern "C" void kernel_launch(void* const* d_in, const int* in_sizes, int n_in,
                              void* d_out, int out_size, void* d_ws, size_t ws_size,
                              hipStream_t stream) {
    const float* re = (const float*)d_in[0];
    const float* im = (const float*)d_in[1];
    float* out = (float*)d_out;
    const int rows = in_sizes[0] / NFFT;          // 8*4096 = 32768
    const size_t im_off = (size_t)in_sizes[0];    // output: [re | im] concatenated

    hipLaunchKernelGGL(ifft1024_kernel, dim3(rows), dim3(NT), 0, stream,
                       re, im, out, im_off);
}